// Round 2
// baseline (383.617 us; speedup 1.0000x reference)
//
#include <hip/hip_runtime.h>
#include <cstdint>
#include <cstddef>

#define BB 32
#define EV 5
#define LL 130
#define HH 768
#define KK 21
#define LP 160   // padded L (10 x 16 MFMA tiles)
#define SST 168  // LDS S-tile row stride in shorts (336B: 16B-aligned, gcd trick for banks)

typedef __attribute__((ext_vector_type(8))) __bf16 bf16x8;
typedef __attribute__((ext_vector_type(4))) float f32x4;

__device__ __forceinline__ unsigned short f2bf(float f) {
    unsigned int u = __float_as_uint(f);
    u += 0x7FFFu + ((u >> 16) & 1u);   // RNE: critical so that ||hn||^2 stays ~1
    return (unsigned short)(u >> 16);
}
__device__ __forceinline__ float bf2f(unsigned int s) {
    return __uint_as_float(s << 16);
}

// ---------------------------------------------------------------------------
// K1: L2-normalize hiddens rows -> bf16, padded to LP rows per n (pad = 0)
// ---------------------------------------------------------------------------
__global__ __launch_bounds__(256) void k_normalize(const float* __restrict__ hid,
                                                   unsigned short* __restrict__ hnbf) {
    int wave = threadIdx.x >> 6, lane = threadIdx.x & 63;
    int r = blockIdx.x * 4 + wave;          // 0 .. 160*160-1
    int n = r / LP, q = r % LP;
    unsigned short* dst = hnbf + (size_t)r * HH;
    if (q < LL) {
        const float4* s4 = (const float4*)(hid + ((size_t)n * LL + q) * HH);
        float4 v0 = s4[lane], v1 = s4[lane + 64], v2 = s4[lane + 128];
        float ss = v0.x*v0.x + v0.y*v0.y + v0.z*v0.z + v0.w*v0.w
                 + v1.x*v1.x + v1.y*v1.y + v1.z*v1.z + v1.w*v1.w
                 + v2.x*v2.x + v2.y*v2.y + v2.z*v2.z + v2.w*v2.w;
        #pragma unroll
        for (int m = 1; m < 64; m <<= 1) ss += __shfl_xor(ss, m, 64);
        float sc = 1.0f / fmaxf(sqrtf(ss), 1e-12f);
        ushort4 o0, o1, o2;
        o0.x = f2bf(v0.x*sc); o0.y = f2bf(v0.y*sc); o0.z = f2bf(v0.z*sc); o0.w = f2bf(v0.w*sc);
        o1.x = f2bf(v1.x*sc); o1.y = f2bf(v1.y*sc); o1.z = f2bf(v1.z*sc); o1.w = f2bf(v1.w*sc);
        o2.x = f2bf(v2.x*sc); o2.y = f2bf(v2.y*sc); o2.z = f2bf(v2.z*sc); o2.w = f2bf(v2.w*sc);
        ushort4* d4 = (ushort4*)dst;
        d4[lane] = o0; d4[lane + 64] = o1; d4[lane + 128] = o2;
    } else {
        ushort4 z; z.x = z.y = z.z = z.w = 0;
        ushort4* d4 = (ushort4*)dst;
        d4[lane] = z; d4[lane + 64] = z; d4[lane + 128] = z;
    }
}

// K1b: convert Wg1 to bf16
__global__ __launch_bounds__(256) void k_cvt_wg1(const float* __restrict__ w,
                                                 unsigned short* __restrict__ o) {
    int idx = blockIdx.x * 256 + threadIdx.x;
    if (idx < 128 * 1536) o[idx] = f2bf(w[idx]);
}

// K1c: fill pooled half of gating input matrix Xg[row = (b*5+i)*5+e][0:768]
__global__ __launch_bounds__(256) void k_xg_pooled(const float* __restrict__ pooled,
                                                   unsigned short* __restrict__ xg) {
    int row = blockIdx.x;                  // 0..799
    int bi = row / 5;                      // b*5+i
    const float* src = pooled + (size_t)bi * HH;
    unsigned short* dst = xg + (size_t)row * 1536;
    #pragma unroll
    for (int j = 0; j < 3; j++) { int h = threadIdx.x + j * 256; dst[h] = f2bf(src[h]); }
}

// ---------------------------------------------------------------------------
// K2: FUSED sim-GEMM + kernel-pool. Block bid=(b*5+e)*5+i:
//   phase 1: S[q][d] = hn[b,e][q,:].hn[b,i][d,:] via MFMA -> bf16 S-tile in LDS
//   phase 2: pool+log+W_att dot -> score (diag blocks also -> sel)
// Gaussian-grid trick: exp(-50(s-mu_k)^2) = C_k * u * r^(k-1),
//   u=exp(-50 s^2+95 s), r=exp(-10 s), C_k=exp(-50 mu_k^2); k=0 direct.
// ---------------------------------------------------------------------------
template <bool DIAG>
__device__ __forceinline__ void pool_phase(
    int b, int e, int i, int ne,
    const unsigned short* Sbf,
    const float* __restrict__ batt, const float* __restrict__ bsel,
    float* __restrict__ score, float* __restrict__ sel,
    const float* wdA, const float* wdE, const float* wqC,
    const float* WaL, const float* WsL, const float* CkL, float* red) {

    const float LOG2E = 1.4426950408889634f;
    const float CA = -50.0f * LOG2E;
    const float CB = 95.0f * LOG2E;
    const float CR = -10.0f * LOG2E;
    const float C0 = -500000.0f * LOG2E;
    int tid = threadIdx.x;

    float selNum = 0.0f;
    for (int base = 0; base < LL; base += 128) {
        int row = base + (tid >> 1);
        int dg = tid & 1;
        bool live = (row < LL);
        float a0[KK], a2[KK];
        #pragma unroll
        for (int k = 0; k < KK; k++) { a0[k] = 0.0f; if (DIAG) a2[k] = 0.0f; }
        if (live) {
            int jmax = dg ? 8 : 9;          // cover d in [0,136): live d < 130
            for (int j = 0; j < jmax; j++) {
                int d0 = dg * 8 + j * 16;
                uint4 v = *(const uint4*)&Sbf[row * SST + d0];
                float sv[8];
                sv[0] = bf2f(v.x & 0xFFFFu); sv[1] = bf2f(v.x >> 16);
                sv[2] = bf2f(v.y & 0xFFFFu); sv[3] = bf2f(v.y >> 16);
                sv[4] = bf2f(v.z & 0xFFFFu); sv[5] = bf2f(v.z >> 16);
                sv[6] = bf2f(v.w & 0xFFFFu); sv[7] = bf2f(v.w >> 16);
                #pragma unroll
                for (int m = 0; m < 8; m++) {
                    int d = d0 + m;
                    float w = wdA[d];
                    float w2 = DIAG ? wdE[d] : 0.0f;
                    float s = sv[m];
                    float s2 = s * s;
                    float pe = exp2f(fmaf(CB, s, CA * s2));
                    float rr = exp2f(CR * s);
                    float sm1 = s - 1.0f;
                    float e0 = exp2f(C0 * (sm1 * sm1));
                    a0[0] = fmaf(w, e0, a0[0]);
                    if (DIAG) a2[0] = fmaf(w2, e0, a2[0]);
                    float p = pe;
                    #pragma unroll
                    for (int k = 1; k < KK; k++) {
                        a0[k] = fmaf(w, p, a0[k]);
                        if (DIAG) a2[k] = fmaf(w2, p, a2[k]);
                        p *= rr;
                    }
                }
            }
        }
        #pragma unroll
        for (int k = 0; k < KK; k++) {
            a0[k] += __shfl_xor(a0[k], 1, 64);
            if (DIAG) a2[k] += __shfl_xor(a2[k], 1, 64);
        }
        if (live && dg == 0) {
            float sc = batt[0];
            #pragma unroll
            for (int k = 0; k < KK; k++) {
                float ps = fmaxf(CkL[k] * a0[k], 1e-10f);
                sc += WaL[k] * __logf(ps);
            }
            score[(size_t)((b * 5 + i) * 5 + e) * LP + row] = sc;
            if (DIAG) {
                float cq = 0.0f;
                #pragma unroll
                for (int k = 0; k < KK; k++) {
                    float ps = fmaxf(CkL[k] * a2[k], 1e-10f);
                    cq += WsL[k] * __logf(ps);
                }
                selNum += wqC[row] * cq;
            }
        }
    }
    if (DIAG) {
        red[tid] = selNum; __syncthreads();
        for (int s = 128; s > 0; s >>= 1) {
            if (tid < s) red[tid] += red[tid + s];
            __syncthreads();
        }
        float tot = red[0]; __syncthreads();
        red[tid] = (tid < LP) ? wqC[tid] : 0.0f; __syncthreads();
        for (int s = 128; s > 0; s >>= 1) {
            if (tid < s) red[tid] += red[tid + s];
            __syncthreads();
        }
        if (tid == 0) sel[ne] = bsel[0] + tot / (red[0] + 1e-10f);
    }
}

__global__ __launch_bounds__(256) void k_simpool(const unsigned short* __restrict__ hnbf,
        const int* __restrict__ msk, const int* __restrict__ seg,
        const float* __restrict__ Watt, const float* __restrict__ batt,
        const float* __restrict__ Wsel, const float* __restrict__ bsel,
        float* __restrict__ score, float* __restrict__ sel) {
    __shared__ __align__(16) char umem[LP * SST * 2];   // union: {As|Bs staging} / Sbf tile
    __shared__ float wdA[LP], wdE[LP], wqC[LP];
    __shared__ float WaL[KK], WsL[KK], CkL[KK];
    __shared__ float red[256];
    unsigned short* As = (unsigned short*)umem;
    unsigned short* Bs = As + LP * 32;
    unsigned short* Sbf = (unsigned short*)umem;

    int bid = blockIdx.x;
    int b = bid / 25, e = (bid / 5) % 5, i = bid % 5;
    int ne = b * 5 + e, ni = b * 5 + i;
    int tid = threadIdx.x, lane = tid & 63, wave = tid >> 6;
    int quad = lane >> 4, l16 = lane & 15;

    // masks + constants into LDS (visible after first K-loop barrier)
    if (tid < LP) {
        int d = tid;
        float mtI = (d >= 1 && d < LL) ? (float)msk[ni * LL + d] : 0.0f;
        wdA[d] = mtI;
        float mtE = (d >= 1 && d < LL) ? (float)msk[ne * LL + d] : 0.0f;
        float sgE = (d < LL) ? (float)seg[ne * LL + d] : 0.0f;
        wdE[d] = sgE * mtE;                  // mask_ev for evidence ne
        wqC[d] = (1.0f - sgE) * mtE;         // mask_claim for evidence ne
    }
    if (tid < KK) {
        const float LOG2E = 1.4426950408889634f;
        WaL[tid] = Watt[tid];
        WsL[tid] = Wsel[tid];
        float mu = 0.95f - 0.1f * (tid - 1);
        CkL[tid] = (tid == 0) ? 1.0f : exp2f(-50.0f * LOG2E * mu * mu);
    }

    // ---------------- GEMM phase ----------------
    const unsigned short* A = hnbf + (size_t)ne * LP * HH;
    const unsigned short* B = hnbf + (size_t)ni * LP * HH;
    int wm = (wave & 1) * 5, wn = (wave >> 1) * 5;
    f32x4 acc[5][5];
    #pragma unroll
    for (int mt = 0; mt < 5; mt++)
        #pragma unroll
        for (int nt = 0; nt < 5; nt++) acc[mt][nt] = (f32x4){0.f, 0.f, 0.f, 0.f};

    for (int k0 = 0; k0 < HH; k0 += 32) {
        #pragma unroll
        for (int it = 0; it < 3; ++it) {
            int s = tid + it * 256;
            if (s < LP * 4) {
                int row = s >> 2, sg = s & 3;
                *(uint4*)&As[s * 8] = *(const uint4*)(A + (size_t)row * HH + k0 + sg * 8);
                *(uint4*)&Bs[s * 8] = *(const uint4*)(B + (size_t)row * HH + k0 + sg * 8);
            }
        }
        __syncthreads();
        bf16x8 af[5], bfr[5];
        #pragma unroll
        for (int t = 0; t < 5; t++) {
            af[t]  = *(const bf16x8*)&As[((wm + t) * 16 + l16) * 32 + quad * 8];
            bfr[t] = *(const bf16x8*)&Bs[((wn + t) * 16 + l16) * 32 + quad * 8];
        }
        #pragma unroll
        for (int mt = 0; mt < 5; mt++)
            #pragma unroll
            for (int nt = 0; nt < 5; nt++)
                acc[mt][nt] = __builtin_amdgcn_mfma_f32_16x16x32_bf16(af[mt], bfr[nt], acc[mt][nt], 0, 0, 0);
        __syncthreads();
    }

    // ---------------- S -> LDS (overwrites staging; all frag reads are done) ---
    #pragma unroll
    for (int mt = 0; mt < 5; mt++)
        #pragma unroll
        for (int nt = 0; nt < 5; nt++) {
            int Rb = (wm + mt) * 16 + quad * 4;
            int C = (wn + nt) * 16 + l16;
            #pragma unroll
            for (int reg = 0; reg < 4; reg++)
                Sbf[(Rb + reg) * SST + C] = f2bf(acc[mt][nt][reg]);
        }
    __syncthreads();

    // ---------------- pool phase ----------------
    if (e == i)
        pool_phase<true>(b, e, i, ne, Sbf, batt, bsel, score, sel,
                         wdA, wdE, wqC, WaL, WsL, CkL, red);
    else
        pool_phase<false>(b, e, i, ne, Sbf, batt, bsel, score, sel,
                          wdA, wdE, wqC, WaL, WsL, CkL, red);
}

// ---------------------------------------------------------------------------
// K3a: per (b,e): masked softmax over q of score for each i -> attg[be][i][q]
// ---------------------------------------------------------------------------
__global__ __launch_bounds__(256) void k_att(const float* __restrict__ score,
        const int* __restrict__ msk, float* __restrict__ attg) {
    int be = blockIdx.x;                 // b*5+e
    int b = be / 5, e = be % 5;
    __shared__ float red[256];
    int tid = threadIdx.x;

    for (int i = 0; i < 5; i++) {
        float val = -1e30f;
        if (tid < LL) {
            float mt = (tid >= 1) ? (float)msk[be * LL + tid] : 0.0f;
            float raw = score[(size_t)((b * 5 + i) * 5 + e) * LP + tid];
            val = (mt > 0.0f) ? raw : -1e4f;
        }
        red[tid] = val; __syncthreads();
        for (int s = 128; s > 0; s >>= 1) {
            if (tid < s) red[tid] = fmaxf(red[tid], red[tid + s]);
            __syncthreads();
        }
        float mx = red[0]; __syncthreads();
        float ex = (tid < LL) ? __expf(val - mx) : 0.0f;
        red[tid] = ex; __syncthreads();
        for (int s = 128; s > 0; s >>= 1) {
            if (tid < s) red[tid] += red[tid + s];
            __syncthreads();
        }
        float Z = red[0]; __syncthreads();
        if (tid < LL) attg[(size_t)(be * 5 + i) * LL + tid] = ex / Z;
    }
}

// ---------------------------------------------------------------------------
// K3b: partial denoise over a q-chunk (26 q's): part[qc][be][i][h]
// grid = 800: bid -> be = bid/5, qc = bid%5
// ---------------------------------------------------------------------------
__global__ __launch_bounds__(256) void k_den1(const float* __restrict__ attg,
        const float* __restrict__ hid, float* __restrict__ part) {
    int bid = blockIdx.x;
    int be = bid / 5, qc = bid % 5;
    int tid = threadIdx.x;
    int q0 = qc * 26;
    float acc[5][3];
    #pragma unroll
    for (int i = 0; i < 5; i++)
        #pragma unroll
        for (int j = 0; j < 3; j++) acc[i][j] = 0.0f;

    for (int t = 0; t < 26; t++) {
        int q = q0 + t;
        float w[5];
        #pragma unroll
        for (int i = 0; i < 5; i++) w[i] = attg[(size_t)(be * 5 + i) * LL + q];
        #pragma unroll
        for (int j = 0; j < 3; j++) {
            float hv = hid[((size_t)be * LL + q) * HH + tid + j * 256];
            #pragma unroll
            for (int i = 0; i < 5; i++) acc[i][j] += w[i] * hv;
        }
    }
    #pragma unroll
    for (int i = 0; i < 5; i++)
        #pragma unroll
        for (int j = 0; j < 3; j++)
            part[((size_t)(qc * 160 + be) * 5 + i) * HH + tid + j * 256] = acc[i][j];
}

// ---------------------------------------------------------------------------
// K3c: reduce the 5 q-chunk partials -> denoise (f32) + Xg bf16 half
// grid = 800: bid -> be = bid/5, i = bid%5
// ---------------------------------------------------------------------------
__global__ __launch_bounds__(256) void k_den2(const float* __restrict__ part,
        float* __restrict__ denoise, unsigned short* __restrict__ xg) {
    int bid = blockIdx.x;
    int be = bid / 5, i = bid % 5;
    int b = be / 5, e = be % 5;
    int tid = threadIdx.x;
    #pragma unroll
    for (int j = 0; j < 3; j++) {
        int h = tid + j * 256;
        float v = 0.0f;
        #pragma unroll
        for (int qc = 0; qc < 5; qc++)
            v += part[((size_t)(qc * 160 + be) * 5 + i) * HH + h];
        denoise[(((size_t)i * BB + b) * 5 + e) * HH + h] = v;
        xg[(size_t)((b * 5 + i) * 5 + e) * 1536 + HH + h] = f2bf(v);
    }
}

// ---------------------------------------------------------------------------
// K4: gating GEMM  Cg[800][128] = Xg[800][1536] @ Wg1^T  (bf16 MFMA)
// ---------------------------------------------------------------------------
__global__ __launch_bounds__(256) void k_gate_gemm(const unsigned short* __restrict__ xg,
        const unsigned short* __restrict__ wg1b, float* __restrict__ cg) {
    int m0 = blockIdx.x * 32;
    __shared__ unsigned short As[32 * 32];
    __shared__ unsigned short Bs[128 * 32];
    int tid = threadIdx.x, lane = tid & 63, wave = tid >> 6;
    int quad = lane >> 4, l16 = lane & 15;
    int wm = wave & 1, wnb = (wave >> 1) * 4;
    f32x4 acc[4];
    #pragma unroll
    for (int nt = 0; nt < 4; nt++) acc[nt] = (f32x4){0.f, 0.f, 0.f, 0.f};

    for (int k0 = 0; k0 < 1536; k0 += 32) {
        if (tid < 128) {
            int row = tid >> 2, sg = tid & 3;
            *(uint4*)&As[tid * 8] = *(const uint4*)(xg + (size_t)(m0 + row) * 1536 + k0 + sg * 8);
        }
        #pragma unroll
        for (int it = 0; it < 2; it++) {
            int s = tid + it * 256;
            int row = s >> 2, sg = s & 3;
            *(uint4*)&Bs[s * 8] = *(const uint4*)(wg1b + (size_t)row * 1536 + k0 + sg * 8);
        }
        __syncthreads();
        bf16x8 af = *(const bf16x8*)&As[(wm * 16 + l16) * 32 + quad * 8];
        #pragma unroll
        for (int nt = 0; nt < 4; nt++) {
            bf16x8 bfr = *(const bf16x8*)&Bs[((wnb + nt) * 16 + l16) * 32 + quad * 8];
            acc[nt] = __builtin_amdgcn_mfma_f32_16x16x32_bf16(af, bfr, acc[nt], 0, 0, 0);
        }
        __syncthreads();
    }
    #pragma unroll
    for (int nt = 0; nt < 4; nt++)
        #pragma unroll
        for (int reg = 0; reg < 4; reg++) {
            int R = m0 + wm * 16 + quad * 4 + reg;
            int C = (wnb + nt) * 16 + l16;
            cg[(size_t)R * 128 + C] = acc[nt][reg];
        }
}

// ---------------------------------------------------------------------------
// K5: per (b,i): g[e] = Wg2 . relu(Cg_row + bg1) + bg2 ; w_de = softmax_e ;
// de = sum_e w_de[e]*denoise ; feat[c] = concat(pooled,de) . Wd[c] + bd[c]
// ---------------------------------------------------------------------------
__global__ __launch_bounds__(256) void k_gate_epilogue(const float* __restrict__ cg,
        const float* __restrict__ bg1, const float* __restrict__ wg2,
        const float* __restrict__ bg2, const float* __restrict__ denoise,
        const float* __restrict__ pooled, const float* __restrict__ wd,
        const float* __restrict__ bd, float* __restrict__ feat) {
    int bi = blockIdx.x;                 // b*5+i
    int b = bi / 5, i = bi % 5;
    __shared__ float red[256];
    __shared__ float gL[5];
    __shared__ float deL[HH];
    int tid = threadIdx.x;

    for (int e = 0; e < 5; e++) {
        float v = 0.0f;
        if (tid < 128) {
            float c = cg[(size_t)(bi * 5 + e) * 128 + tid] + bg1[tid];
            v = wg2[tid] * fmaxf(c, 0.0f);
        }
        red[tid] = v; __syncthreads();
        for (int s = 128; s > 0; s >>= 1) {
            if (tid < s) red[tid] += red[tid + s];
            __syncthreads();
        }
        if (tid == 0) gL[e] = red[0] + bg2[0];
        __syncthreads();
    }
    float m = gL[0];
    #pragma unroll
    for (int e = 1; e < 5; e++) m = fmaxf(m, gL[e]);
    float wde[5]; float z = 0.0f;
    #pragma unroll
    for (int e = 0; e < 5; e++) { wde[e] = __expf(gL[e] - m); z += wde[e]; }
    #pragma unroll
    for (int e = 0; e < 5; e++) wde[e] /= z;

    #pragma unroll
    for (int j = 0; j < 3; j++) {
        int h = tid + j * 256;
        float v = 0.0f;
        #pragma unroll
        for (int e = 0; e < 5; e++)
            v += wde[e] * denoise[(((size_t)i * BB + b) * 5 + e) * HH + h];
        deL[h] = v;
    }
    __syncthreads();

    float part[3] = {0.0f, 0.0f, 0.0f};
    for (int mm = 0; mm < 6; mm++) {
        int h = tid + mm * 256;
        float x = (h < HH) ? pooled[(size_t)bi * HH + h] : deL[h - HH];
        #pragma unroll
        for (int c = 0; c < 3; c++) part[c] += x * wd[(size_t)c * 1536 + h];
    }
    for (int c = 0; c < 3; c++) {
        red[tid] = part[c]; __syncthreads();
        for (int s = 128; s > 0; s >>= 1) {
            if (tid < s) red[tid] += red[tid + s];
            __syncthreads();
        }
        if (tid == 0) feat[bi * 3 + c] = red[0] + bd[c];
        __syncthreads();
    }
}

// ---------------------------------------------------------------------------
// K6: final combine: select softmax over i, class softmax over c, log(prob)
// ---------------------------------------------------------------------------
__global__ __launch_bounds__(64) void k_final(const float* __restrict__ sel,
        const float* __restrict__ feat, float* __restrict__ out) {
    int b = threadIdx.x;
    if (b >= BB) return;
    float sv[5]; float m = -1e30f;
    #pragma unroll
    for (int i = 0; i < 5; i++) { sv[i] = sel[b * 5 + i]; m = fmaxf(m, sv[i]); }
    float z = 0.0f;
    #pragma unroll
    for (int i = 0; i < 5; i++) { sv[i] = __expf(sv[i] - m); z += sv[i]; }
    #pragma unroll
    for (int i = 0; i < 5; i++) sv[i] /= z;
    float prob[3] = {0.0f, 0.0f, 0.0f};
    #pragma unroll
    for (int i = 0; i < 5; i++) {
        float f0 = feat[(b * 5 + i) * 3 + 0];
        float f1 = feat[(b * 5 + i) * 3 + 1];
        float f2 = feat[(b * 5 + i) * 3 + 2];
        float mm = fmaxf(f0, fmaxf(f1, f2));
        float e0 = __expf(f0 - mm), e1 = __expf(f1 - mm), e2 = __expf(f2 - mm);
        float zz = e0 + e1 + e2;
        prob[0] += sv[i] * e0 / zz;
        prob[1] += sv[i] * e1 / zz;
        prob[2] += sv[i] * e2 / zz;
    }
    #pragma unroll
    for (int c = 0; c < 3; c++) out[b * 3 + c] = __logf(prob[c]);
}

// ---------------------------------------------------------------------------
extern "C" void kernel_launch(void* const* d_in, const int* in_sizes, int n_in,
                              void* d_out, int out_size, void* d_ws, size_t ws_size,
                              hipStream_t stream) {
    const float* hiddens = (const float*)d_in[0];
    const float* pooled  = (const float*)d_in[1];
    const int*   msk     = (const int*)d_in[2];
    const int*   seg     = (const int*)d_in[3];
    const float* Watt    = (const float*)d_in[4];
    const float* batt    = (const float*)d_in[5];
    const float* Wsel    = (const float*)d_in[6];
    const float* bsel    = (const float*)d_in[7];
    const float* Wg1     = (const float*)d_in[8];
    const float* bg1     = (const float*)d_in[9];
    const float* Wg2     = (const float*)d_in[10];
    const float* bg2     = (const float*)d_in[11];
    const float* Wd      = (const float*)d_in[12];
    const float* bd      = (const float*)d_in[13];

    char* ws = (char*)d_ws;
    size_t off = 0;
    auto alloc = [&](size_t bytes) -> void* {
        void* p = ws + off;
        off += (bytes + 255) & ~(size_t)255;
        return p;
    };
    unsigned short* hnbf   = (unsigned short*)alloc((size_t)160 * LP * HH * 2);  // 39.3 MB
    float*          score  = (float*)alloc((size_t)800 * LP * 4);
    float*          sel    = (float*)alloc((size_t)160 * 4);
    float*          attg   = (float*)alloc((size_t)800 * LL * 4);
    float*          part   = (float*)alloc((size_t)5 * 160 * 5 * HH * 4);        // 12.3 MB
    float*          denoise= (float*)alloc((size_t)5 * BB * 5 * HH * 4);
    unsigned short* xg     = (unsigned short*)alloc((size_t)800 * 1536 * 2);
    unsigned short* wg1b   = (unsigned short*)alloc((size_t)128 * 1536 * 2);
    float*          cg     = (float*)alloc((size_t)800 * 128 * 4);
    float*          feat   = (float*)alloc((size_t)800 * 3 * 4);
    (void)ws_size; (void)in_sizes; (void)n_in; (void)out_size;

    k_normalize<<<dim3(160 * LP / 4), dim3(256), 0, stream>>>(hiddens, hnbf);
    k_cvt_wg1<<<dim3(768), dim3(256), 0, stream>>>(Wg1, wg1b);
    k_xg_pooled<<<dim3(800), dim3(256), 0, stream>>>(pooled, xg);
    k_simpool<<<dim3(800), dim3(256), 0, stream>>>(hnbf, msk, seg, Watt, batt, Wsel, bsel, score, sel);
    k_att<<<dim3(160), dim3(256), 0, stream>>>(score, msk, attg);
    k_den1<<<dim3(800), dim3(256), 0, stream>>>(attg, hiddens, part);
    k_den2<<<dim3(800), dim3(256), 0, stream>>>(part, denoise, xg);
    k_gate_gemm<<<dim3(25), dim3(256), 0, stream>>>(xg, wg1b, cg);
    k_gate_epilogue<<<dim3(160), dim3(256), 0, stream>>>(cg, bg1, Wg2, bg2, denoise, pooled, Wd, bd, feat);
    k_final<<<dim3(1), dim3(64), 0, stream>>>(sel, feat, (float*)d_out);
}

// Round 3
// 295.722 us; speedup vs baseline: 1.2972x; 1.2972x over previous
//
#include <hip/hip_runtime.h>
#include <cstdint>
#include <cstddef>

#define BB 32
#define EV 5
#define LL 130
#define HH 768
#define KK 21
#define LP 160   // padded L for S tiles (10 x 16 MFMA tiles)

typedef __attribute__((ext_vector_type(8))) __bf16 bf16x8;
typedef __attribute__((ext_vector_type(4))) float f32x4;

__device__ __forceinline__ unsigned short f2bf(float f) {
    unsigned int u = __float_as_uint(f);
    u += 0x7FFFu + ((u >> 16) & 1u);   // RNE: keeps ||hn||^2 = 1 +- ~1e-4 (sigma=0.001 kernel!)
    return (unsigned short)(u >> 16);
}
__device__ __forceinline__ float bf2f(unsigned int s) {
    return __uint_as_float(s << 16);
}

// ---------------------------------------------------------------------------
// K1: L2-normalize hiddens rows -> bf16. hnbf has 130 rows per n (no padding).
// row r = n*130+q is contiguous in both src and dst -> pure row stream.
// ---------------------------------------------------------------------------
__global__ __launch_bounds__(256) void k_normalize(const float* __restrict__ hid,
                                                   unsigned short* __restrict__ hnbf) {
    int wave = threadIdx.x >> 6, lane = threadIdx.x & 63;
    int r = blockIdx.x * 4 + wave;          // 0 .. 20800
    if (r >= 160 * LL) return;
    const float4* s4 = (const float4*)(hid + (size_t)r * HH);
    float4 v0 = s4[lane], v1 = s4[lane + 64], v2 = s4[lane + 128];
    float ss = v0.x*v0.x + v0.y*v0.y + v0.z*v0.z + v0.w*v0.w
             + v1.x*v1.x + v1.y*v1.y + v1.z*v1.z + v1.w*v1.w
             + v2.x*v2.x + v2.y*v2.y + v2.z*v2.z + v2.w*v2.w;
    #pragma unroll
    for (int m = 1; m < 64; m <<= 1) ss += __shfl_xor(ss, m, 64);
    float sc = 1.0f / fmaxf(sqrtf(ss), 1e-12f);
    ushort4 o0, o1, o2;
    o0.x = f2bf(v0.x*sc); o0.y = f2bf(v0.y*sc); o0.z = f2bf(v0.z*sc); o0.w = f2bf(v0.w*sc);
    o1.x = f2bf(v1.x*sc); o1.y = f2bf(v1.y*sc); o1.z = f2bf(v1.z*sc); o1.w = f2bf(v1.w*sc);
    o2.x = f2bf(v2.x*sc); o2.y = f2bf(v2.y*sc); o2.z = f2bf(v2.z*sc); o2.w = f2bf(v2.w*sc);
    ushort4* d4 = (ushort4*)(hnbf + (size_t)r * HH);
    d4[lane] = o0; d4[lane + 64] = o1; d4[lane + 128] = o2;
}

// K1b: convert Wg1 to bf16
__global__ __launch_bounds__(256) void k_cvt_wg1(const float* __restrict__ w,
                                                 unsigned short* __restrict__ o) {
    int idx = blockIdx.x * 256 + threadIdx.x;
    if (idx < 128 * 1536) o[idx] = f2bf(w[idx]);
}

// K1c: fill pooled half of gating input Xg[row = (b*5+i)*5+e][0:768]
__global__ __launch_bounds__(256) void k_xg_pooled(const float* __restrict__ pooled,
                                                   unsigned short* __restrict__ xg) {
    int row = blockIdx.x;                  // 0..799
    int bi = row / 5;
    const float* src = pooled + (size_t)bi * HH;
    unsigned short* dst = xg + (size_t)row * 1536;
    #pragma unroll
    for (int j = 0; j < 3; j++) { int h = threadIdx.x + j * 256; dst[h] = f2bf(src[h]); }
}

// ---------------------------------------------------------------------------
// K2: batched similarity GEMM. block bid=(b*5+e)*5+i computes
// S[q][d] = hn[b,e][q,:].hn[b,i][d,:]  (LPxLP bf16 out; rows>=130 are zero)
// ---------------------------------------------------------------------------
__global__ __launch_bounds__(256) void k_sim_gemm(const unsigned short* __restrict__ hnbf,
                                                  unsigned short* __restrict__ Sg) {
    int bid = blockIdx.x;
    int b = bid / 25, e = (bid / 5) % 5, i = bid % 5;
    const unsigned short* A = hnbf + (size_t)(b * 5 + e) * LL * HH;
    const unsigned short* B = hnbf + (size_t)(b * 5 + i) * LL * HH;
    __shared__ unsigned short As[LP * 32];
    __shared__ unsigned short Bs[LP * 32];
    int tid = threadIdx.x, lane = tid & 63, wave = tid >> 6;
    int quad = lane >> 4, l16 = lane & 15;
    int wm = (wave & 1) * 5, wn = (wave >> 1) * 5;
    f32x4 acc[5][5];
    #pragma unroll
    for (int mt = 0; mt < 5; mt++)
        #pragma unroll
        for (int nt = 0; nt < 5; nt++) acc[mt][nt] = (f32x4){0.f, 0.f, 0.f, 0.f};

    for (int k0 = 0; k0 < HH; k0 += 32) {
        #pragma unroll
        for (int it = 0; it < 3; ++it) {
            int s = tid + it * 256;
            if (s < LP * 4) {
                int row = s >> 2, sg = s & 3;
                uint4 va = (uint4){0, 0, 0, 0}, vb = va;
                if (row < LL) {
                    va = *(const uint4*)(A + (size_t)row * HH + k0 + sg * 8);
                    vb = *(const uint4*)(B + (size_t)row * HH + k0 + sg * 8);
                }
                *(uint4*)&As[s * 8] = va;
                *(uint4*)&Bs[s * 8] = vb;
            }
        }
        __syncthreads();
        bf16x8 af[5], bfr[5];
        #pragma unroll
        for (int t = 0; t < 5; t++) {
            af[t]  = *(const bf16x8*)&As[((wm + t) * 16 + l16) * 32 + quad * 8];
            bfr[t] = *(const bf16x8*)&Bs[((wn + t) * 16 + l16) * 32 + quad * 8];
        }
        #pragma unroll
        for (int mt = 0; mt < 5; mt++)
            #pragma unroll
            for (int nt = 0; nt < 5; nt++)
                acc[mt][nt] = __builtin_amdgcn_mfma_f32_16x16x32_bf16(af[mt], bfr[nt], acc[mt][nt], 0, 0, 0);
        __syncthreads();
    }
    size_t base = (size_t)bid * LP * LP;
    #pragma unroll
    for (int mt = 0; mt < 5; mt++)
        #pragma unroll
        for (int nt = 0; nt < 5; nt++) {
            int R = (wm + mt) * 16 + quad * 4;
            int C = (wn + nt) * 16 + l16;
            unsigned short* dst = Sg + base + (size_t)R * LP + C;
            #pragma unroll
            for (int reg = 0; reg < 4; reg++) dst[(size_t)reg * LP] = f2bf(acc[mt][nt][reg]);
        }
}

// ---------------------------------------------------------------------------
// K3: kernel-pool, no big LDS tile. grid 4000: bid = pair*5 + chunk.
// 26 live rows per block, 8 lanes per row streaming 16B uint4 from global.
// Gaussian-grid trick: exp(-50(s-mu_k)^2) = C_k * u * r^(k-1),
//   u=exp(-50 s^2+95 s), r=exp(-10 s), C_k=exp(-50 mu_k^2); k=0 direct.
// Diag pairs also emit per-chunk sel partials (selp/denp).
// ---------------------------------------------------------------------------
template <bool DIAG>
__device__ __forceinline__ void pool_body(
    int pair, int row, int lane8, bool live, int ne, int c,
    const unsigned short* __restrict__ Sg,
    const float* __restrict__ batt,
    float* __restrict__ score, float* __restrict__ selp, float* __restrict__ denp,
    const float* wdA, const float* wdE, const float* wqC,
    const float* WaL, const float* WsL, const float* CkL,
    float* redsel, float* redden) {

    const float LOG2E = 1.4426950408889634f;
    const float CA = -50.0f * LOG2E;
    const float CB = 95.0f * LOG2E;
    const float CR = -10.0f * LOG2E;
    const float C0 = -500000.0f * LOG2E;
    int tid = threadIdx.x;

    float a0[KK], a2[KK];
    #pragma unroll
    for (int k = 0; k < KK; k++) { a0[k] = 0.0f; a2[k] = 0.0f; }

    auto proc = [&](float s, int d) {
        float w = wdA[d];
        float w2 = DIAG ? wdE[d] : 0.0f;
        float pe = exp2f(fmaf(CB, s, CA * s * s));
        float rr = exp2f(CR * s);
        float sm1 = s - 1.0f;
        float e0 = exp2f(C0 * (sm1 * sm1));
        a0[0] = fmaf(w, e0, a0[0]);
        if (DIAG) a2[0] = fmaf(w2, e0, a2[0]);
        float p = pe;
        #pragma unroll
        for (int k = 1; k < KK; k++) {
            a0[k] = fmaf(w, p, a0[k]);
            if (DIAG) a2[k] = fmaf(w2, p, a2[k]);
            p *= rr;
        }
    };

    if (live) {
        const unsigned short* Srow = Sg + (size_t)pair * LP * LP + (size_t)row * LP;
        #pragma unroll
        for (int j = 0; j < 2; j++) {
            uint4 v = *(const uint4*)(Srow + lane8 * 8 + j * 64);
            int d0 = lane8 * 8 + j * 64;
            proc(bf2f(v.x & 0xFFFFu), d0 + 0); proc(bf2f(v.x >> 16), d0 + 1);
            proc(bf2f(v.y & 0xFFFFu), d0 + 2); proc(bf2f(v.y >> 16), d0 + 3);
            proc(bf2f(v.z & 0xFFFFu), d0 + 4); proc(bf2f(v.z >> 16), d0 + 5);
            proc(bf2f(v.w & 0xFFFFu), d0 + 6); proc(bf2f(v.w >> 16), d0 + 7);
        }
        proc(bf2f((unsigned int)Srow[128 + lane8]), 128 + lane8);  // d in [128,136)
    }
    // reduce across the 8 lanes of each row
    #pragma unroll
    for (int k = 0; k < KK; k++) {
        a0[k] += __shfl_xor(a0[k], 1, 64);
        a0[k] += __shfl_xor(a0[k], 2, 64);
        a0[k] += __shfl_xor(a0[k], 4, 64);
        if (DIAG) {
            a2[k] += __shfl_xor(a2[k], 1, 64);
            a2[k] += __shfl_xor(a2[k], 2, 64);
            a2[k] += __shfl_xor(a2[k], 4, 64);
        }
    }
    float selv = 0.0f, denv = 0.0f;
    if (live && lane8 == 0) {
        float sc = batt[0];
        #pragma unroll
        for (int k = 0; k < KK; k++)
            sc += WaL[k] * __logf(fmaxf(CkL[k] * a0[k], 1e-10f));
        score[(size_t)pair * LP + row] = sc;
        if (DIAG) {
            float cq = 0.0f;
            #pragma unroll
            for (int k = 0; k < KK; k++)
                cq += WsL[k] * __logf(fmaxf(CkL[k] * a2[k], 1e-10f));
            selv = wqC[row] * cq;
            denv = wqC[row];
        }
    }
    if (DIAG) {
        #pragma unroll
        for (int m = 8; m < 64; m <<= 1) {
            selv += __shfl_xor(selv, m, 64);
            denv += __shfl_xor(denv, m, 64);
        }
        int wave = tid >> 6, lane = tid & 63;
        if (lane == 0) { redsel[wave] = selv; redden[wave] = denv; }
        __syncthreads();
        if (tid == 0) {
            selp[ne * 5 + c] = redsel[0] + redsel[1] + redsel[2] + redsel[3];
            denp[ne * 5 + c] = redden[0] + redden[1] + redden[2] + redden[3];
        }
    }
}

__global__ __launch_bounds__(256) void k_pool(const unsigned short* __restrict__ Sg,
        const int* __restrict__ msk, const int* __restrict__ seg,
        const float* __restrict__ Watt, const float* __restrict__ batt,
        const float* __restrict__ Wsel,
        float* __restrict__ score, float* __restrict__ selp, float* __restrict__ denp) {
    __shared__ float wdA[136], wdE[136], wqC[136];
    __shared__ float WaL[KK], WsL[KK], CkL[KK];
    __shared__ float redsel[4], redden[4];
    int bid = blockIdx.x;
    int pair = bid / 5, c = bid % 5;
    int b = pair / 25, e = (pair / 5) % 5, i = pair % 5;
    int ne = b * 5 + e, ni = b * 5 + i;
    int tid = threadIdx.x;

    if (tid < 136) {
        int d = tid;
        wdA[d] = (d >= 1 && d < LL) ? (float)msk[ni * LL + d] : 0.0f;
        float mtE = (d >= 1 && d < LL) ? (float)msk[ne * LL + d] : 0.0f;
        float sgE = (d < LL) ? (float)seg[ne * LL + d] : 0.0f;
        wdE[d] = sgE * mtE;
        wqC[d] = (1.0f - sgE) * mtE;
    }
    if (tid < KK) {
        const float LOG2E = 1.4426950408889634f;
        WaL[tid] = Watt[tid];
        WsL[tid] = Wsel[tid];
        float mu = 0.95f - 0.1f * (tid - 1);
        CkL[tid] = (tid == 0) ? 1.0f : exp2f(-50.0f * LOG2E * mu * mu);
    }
    __syncthreads();

    int row = c * 26 + (tid >> 3);
    int lane8 = tid & 7;
    bool live = (tid < 208);               // 26 rows * 8 lanes

    if (e == i)
        pool_body<true>(pair, row, lane8, live, ne, c, Sg, batt, score, selp, denp,
                        wdA, wdE, wqC, WaL, WsL, CkL, redsel, redden);
    else
        pool_body<false>(pair, row, lane8, live, ne, c, Sg, batt, score, selp, denp,
                         wdA, wdE, wqC, WaL, WsL, CkL, redsel, redden);
}

// ---------------------------------------------------------------------------
// K4: masked softmax. one wave per (be,i): grid 800, block 64.
// ---------------------------------------------------------------------------
__global__ __launch_bounds__(64) void k_att(const float* __restrict__ score,
        const int* __restrict__ msk, float* __restrict__ attg) {
    int bid = blockIdx.x;                 // be*5 + i
    int be = bid / 5, ii = bid % 5;
    int b = be / 5, e = be % 5;
    const float* srow = score + ((size_t)(b * 5 + ii) * 5 + e) * LP;
    int lane = threadIdx.x;

    float v0, v1, v2 = -1e30f;
    {
        int q = lane;
        float mt = (q >= 1 && msk[be * LL + q] != 0) ? 1.0f : 0.0f;
        v0 = (mt > 0.0f) ? srow[q] : -1e4f;
    }
    {
        int q = lane + 64;
        float mt = (msk[be * LL + q] != 0) ? 1.0f : 0.0f;
        v1 = (mt > 0.0f) ? srow[q] : -1e4f;
    }
    if (lane < 2) {
        int q = lane + 128;
        float mt = (msk[be * LL + q] != 0) ? 1.0f : 0.0f;
        v2 = (mt > 0.0f) ? srow[q] : -1e4f;
    }
    float mx = fmaxf(v0, fmaxf(v1, v2));
    #pragma unroll
    for (int m = 1; m < 64; m <<= 1) mx = fmaxf(mx, __shfl_xor(mx, m, 64));
    float e0 = __expf(v0 - mx), e1 = __expf(v1 - mx);
    float e2 = (lane < 2) ? __expf(v2 - mx) : 0.0f;
    float Z = e0 + e1 + e2;
    #pragma unroll
    for (int m = 1; m < 64; m <<= 1) Z += __shfl_xor(Z, m, 64);
    float iz = 1.0f / Z;
    attg[(size_t)bid * LL + lane] = e0 * iz;
    attg[(size_t)bid * LL + lane + 64] = e1 * iz;
    if (lane < 2) attg[(size_t)bid * LL + lane + 128] = e2 * iz;
}

// ---------------------------------------------------------------------------
// K5: denoise: de[be,i,h] = sum_q att[be,i,q]*hid[be,q,h]. grid 480 (be,j).
// writes f32 denoise (for epilogue) + bf16 Xg half (for gate GEMM).
// ---------------------------------------------------------------------------
__global__ __launch_bounds__(256) void k_den(const float* __restrict__ attg,
        const float* __restrict__ hid, float* __restrict__ dn,
        unsigned short* __restrict__ xg) {
    int bid = blockIdx.x;
    int be = bid / 3, j = bid % 3;
    int b = be / 5, e = be % 5;
    int tid = threadIdx.x;
    int h = j * 256 + tid;
    __shared__ float attl[5 * LL];
    for (int s = tid; s < 5 * LL; s += 256)
        attl[s] = attg[(size_t)(be * 5) * LL + s];
    __syncthreads();

    float acc[5] = {0.f, 0.f, 0.f, 0.f, 0.f};
    const float* hbase = hid + (size_t)be * LL * HH + h;
    #pragma unroll 2
    for (int q = 0; q < LL; q++) {
        float hv = hbase[(size_t)q * HH];
        #pragma unroll
        for (int i = 0; i < 5; i++) acc[i] = fmaf(attl[i * LL + q], hv, acc[i]);
    }
    #pragma unroll
    for (int i = 0; i < 5; i++) {
        dn[((size_t)be * 5 + i) * HH + h] = acc[i];
        xg[((size_t)(b * 5 + i) * 5 + e) * 1536 + HH + h] = f2bf(acc[i]);
    }
}

// ---------------------------------------------------------------------------
// K6: gating GEMM Cg[800][128] += Xg[800][1536] @ Wg1^T, 3-way K-split,
// f32 atomics into memset-zeroed cg. grid 150: bid = rb*3 + ks.
// ---------------------------------------------------------------------------
__global__ __launch_bounds__(256) void k_gate_gemm(const unsigned short* __restrict__ xg,
        const unsigned short* __restrict__ wg1b, float* __restrict__ cg) {
    int bid = blockIdx.x;
    int rb = bid / 3, ks = bid % 3;
    int m0 = rb * 16;
    __shared__ unsigned short As[16 * 32];
    __shared__ unsigned short Bs[128 * 32];
    int tid = threadIdx.x, lane = tid & 63, wave = tid >> 6;
    int quad = lane >> 4, l16 = lane & 15;
    f32x4 acc[2];
    acc[0] = (f32x4){0.f, 0.f, 0.f, 0.f};
    acc[1] = (f32x4){0.f, 0.f, 0.f, 0.f};

    for (int t = 0; t < 16; t++) {
        int k0 = ks * 512 + t * 32;
        if (tid < 64) {
            int row = tid >> 2, sg = tid & 3;
            *(uint4*)&As[tid * 8] = *(const uint4*)(xg + (size_t)(m0 + row) * 1536 + k0 + sg * 8);
        }
        #pragma unroll
        for (int it = 0; it < 2; it++) {
            int s = tid + it * 256;
            int row = s >> 2, sg = s & 3;
            *(uint4*)&Bs[s * 8] = *(const uint4*)(wg1b + (size_t)row * 1536 + k0 + sg * 8);
        }
        __syncthreads();
        bf16x8 af = *(const bf16x8*)&As[l16 * 32 + quad * 8];
        #pragma unroll
        for (int nt = 0; nt < 2; nt++) {
            int ct = wave * 2 + nt;
            bf16x8 bfr = *(const bf16x8*)&Bs[(ct * 16 + l16) * 32 + quad * 8];
            acc[nt] = __builtin_amdgcn_mfma_f32_16x16x32_bf16(af, bfr, acc[nt], 0, 0, 0);
        }
        __syncthreads();
    }
    #pragma unroll
    for (int nt = 0; nt < 2; nt++) {
        int C = (wave * 2 + nt) * 16 + l16;
        #pragma unroll
        for (int reg = 0; reg < 4; reg++) {
            int R = m0 + quad * 4 + reg;
            atomicAdd(&cg[(size_t)R * 128 + C], acc[nt][reg]);
        }
    }
}

// ---------------------------------------------------------------------------
// K7: per (b,i): g[e] = Wg2.relu(cg+bg1)+bg2; softmax_e; de; feat = Wd.concat
// ---------------------------------------------------------------------------
__global__ __launch_bounds__(256) void k_gate_epi(const float* __restrict__ cg,
        const float* __restrict__ bg1, const float* __restrict__ wg2,
        const float* __restrict__ bg2, const float* __restrict__ dn,
        const float* __restrict__ pooled, const float* __restrict__ wd,
        const float* __restrict__ bd, float* __restrict__ feat) {
    int bi = blockIdx.x;                 // b*5+i
    int b = bi / 5, ii = bi % 5;
    __shared__ float red4[4];
    __shared__ float gL[5];
    __shared__ float deL[HH];
    int tid = threadIdx.x, lane = tid & 63, wave = tid >> 6;

    for (int e = 0; e < 5; e++) {
        float v = 0.0f;
        if (tid < 128) {
            float ccv = cg[(size_t)(bi * 5 + e) * 128 + tid] + bg1[tid];
            v = wg2[tid] * fmaxf(ccv, 0.0f);
        }
        #pragma unroll
        for (int m = 1; m < 64; m <<= 1) v += __shfl_xor(v, m, 64);
        if (lane == 0) red4[wave] = v;
        __syncthreads();
        if (tid == 0) gL[e] = red4[0] + red4[1] + bg2[0];
        __syncthreads();
    }
    float mx = gL[0];
    #pragma unroll
    for (int e = 1; e < 5; e++) mx = fmaxf(mx, gL[e]);
    float wde[5]; float z = 0.0f;
    #pragma unroll
    for (int e = 0; e < 5; e++) { wde[e] = __expf(gL[e] - mx); z += wde[e]; }
    float iz = 1.0f / z;
    #pragma unroll
    for (int e = 0; e < 5; e++) wde[e] *= iz;

    #pragma unroll
    for (int j = 0; j < 3; j++) {
        int h = tid + j * 256;
        float v = 0.0f;
        #pragma unroll
        for (int e = 0; e < 5; e++)
            v += wde[e] * dn[((size_t)(b * 5 + e) * 5 + ii) * HH + h];
        deL[h] = v;
    }
    __syncthreads();

    float part[3] = {0.0f, 0.0f, 0.0f};
    #pragma unroll
    for (int mm = 0; mm < 6; mm++) {
        int h = tid + mm * 256;
        float x = (mm < 3) ? pooled[(size_t)bi * HH + h] : deL[h - HH];
        #pragma unroll
        for (int c = 0; c < 3; c++) part[c] = fmaf(x, wd[(size_t)c * 1536 + h], part[c]);
    }
    #pragma unroll
    for (int c = 0; c < 3; c++) {
        float v = part[c];
        #pragma unroll
        for (int m = 1; m < 64; m <<= 1) v += __shfl_xor(v, m, 64);
        if (lane == 0) red4[wave] = v;
        __syncthreads();
        if (tid == 0) feat[bi * 3 + c] = red4[0] + red4[1] + red4[2] + red4[3] + bd[c];
        __syncthreads();
    }
}

// ---------------------------------------------------------------------------
// K8: final: sel from partials, select softmax over i, class softmax, log
// ---------------------------------------------------------------------------
__global__ __launch_bounds__(64) void k_final(const float* __restrict__ selp,
        const float* __restrict__ denp, const float* __restrict__ bsel,
        const float* __restrict__ feat, float* __restrict__ out) {
    int b = threadIdx.x;
    if (b >= BB) return;
    float sv[5]; float m = -1e30f;
    #pragma unroll
    for (int i = 0; i < 5; i++) {
        float num = 0.0f, den = 0.0f;
        #pragma unroll
        for (int c = 0; c < 5; c++) {
            num += selp[(b * 5 + i) * 5 + c];
            den += denp[(b * 5 + i) * 5 + c];
        }
        sv[i] = bsel[0] + num / (den + 1e-10f);
        m = fmaxf(m, sv[i]);
    }
    float z = 0.0f;
    #pragma unroll
    for (int i = 0; i < 5; i++) { sv[i] = __expf(sv[i] - m); z += sv[i]; }
    #pragma unroll
    for (int i = 0; i < 5; i++) sv[i] /= z;
    float prob[3] = {0.0f, 0.0f, 0.0f};
    #pragma unroll
    for (int i = 0; i < 5; i++) {
        float f0 = feat[(b * 5 + i) * 3 + 0];
        float f1 = feat[(b * 5 + i) * 3 + 1];
        float f2 = feat[(b * 5 + i) * 3 + 2];
        float mm = fmaxf(f0, fmaxf(f1, f2));
        float e0 = __expf(f0 - mm), e1 = __expf(f1 - mm), e2 = __expf(f2 - mm);
        float zz = e0 + e1 + e2;
        prob[0] += sv[i] * e0 / zz;
        prob[1] += sv[i] * e1 / zz;
        prob[2] += sv[i] * e2 / zz;
    }
    #pragma unroll
    for (int c = 0; c < 3; c++) out[b * 3 + c] = __logf(prob[c]);
}

// ---------------------------------------------------------------------------
extern "C" void kernel_launch(void* const* d_in, const int* in_sizes, int n_in,
                              void* d_out, int out_size, void* d_ws, size_t ws_size,
                              hipStream_t stream) {
    const float* hiddens = (const float*)d_in[0];
    const float* pooled  = (const float*)d_in[1];
    const int*   msk     = (const int*)d_in[2];
    const int*   seg     = (const int*)d_in[3];
    const float* Watt    = (const float*)d_in[4];
    const float* batt    = (const float*)d_in[5];
    const float* Wsel    = (const float*)d_in[6];
    const float* bsel    = (const float*)d_in[7];
    const float* Wg1     = (const float*)d_in[8];
    const float* bg1     = (const float*)d_in[9];
    const float* Wg2     = (const float*)d_in[10];
    const float* bg2     = (const float*)d_in[11];
    const float* Wd      = (const float*)d_in[12];
    const float* bd      = (const float*)d_in[13];

    char* ws = (char*)d_ws;
    size_t off = 0;
    auto alloc = [&](size_t bytes) -> void* {
        void* p = ws + off;
        off += (bytes + 255) & ~(size_t)255;
        return p;
    };
    unsigned short* hnbf   = (unsigned short*)alloc((size_t)160 * LL * HH * 2);  // 31.9 MB
    unsigned short* Sg     = (unsigned short*)alloc((size_t)800 * LP * LP * 2);  // 41.0 MB
    float*          score  = (float*)alloc((size_t)800 * LP * 4);
    float*          selp   = (float*)alloc((size_t)160 * 5 * 4);
    float*          denp   = (float*)alloc((size_t)160 * 5 * 4);
    float*          attg   = (float*)alloc((size_t)800 * LL * 4);
    float*          dn     = (float*)alloc((size_t)160 * 5 * HH * 4);            // 2.46 MB
    unsigned short* xg     = (unsigned short*)alloc((size_t)800 * 1536 * 2);
    unsigned short* wg1b   = (unsigned short*)alloc((size_t)128 * 1536 * 2);
    float*          cg     = (float*)alloc((size_t)800 * 128 * 4);
    float*          feat   = (float*)alloc((size_t)800 * 3 * 4);
    (void)ws_size; (void)in_sizes; (void)n_in; (void)out_size;

    hipMemsetAsync(cg, 0, (size_t)800 * 128 * 4, stream);
    k_normalize<<<dim3((160 * LL + 3) / 4), dim3(256), 0, stream>>>(hiddens, hnbf);
    k_cvt_wg1<<<dim3(768), dim3(256), 0, stream>>>(Wg1, wg1b);
    k_xg_pooled<<<dim3(800), dim3(256), 0, stream>>>(pooled, xg);
    k_sim_gemm<<<dim3(800), dim3(256), 0, stream>>>(hnbf, Sg);
    k_pool<<<dim3(4000), dim3(256), 0, stream>>>(Sg, msk, seg, Watt, batt, Wsel, score, selp, denp);
    k_att<<<dim3(800), dim3(64), 0, stream>>>(score, msk, attg);
    k_den<<<dim3(480), dim3(256), 0, stream>>>(attg, hiddens, dn, xg);
    k_gate_gemm<<<dim3(150), dim3(256), 0, stream>>>(xg, wg1b, cg);
    k_gate_epi<<<dim3(160), dim3(256), 0, stream>>>(cg, bg1, Wg2, bg2, dn, pooled, Wd, bd, feat);
    k_final<<<dim3(1), dim3(64), 0, stream>>>(selp, denp, bsel, feat, (float*)d_out);
}

// Round 4
// 281.262 us; speedup vs baseline: 1.3639x; 1.0514x over previous
//
#include <hip/hip_runtime.h>
#include <cstdint>
#include <cstddef>

#define BB 32
#define EV 5
#define LL 130
#define HH 768
#define KK 21
#define LP 160    // score row stride (padded)
#define SD 136    // compact Sg col count (d < 136)
#define SR 130    // compact Sg row count

typedef __attribute__((ext_vector_type(8))) __bf16 bf16x8;
typedef __attribute__((ext_vector_type(4))) float f32x4;

__device__ __forceinline__ unsigned short f2bf(float f) {
    unsigned int u = __float_as_uint(f);
    u += 0x7FFFu + ((u >> 16) & 1u);   // RNE: keeps ||hn||^2 = 1 +- ~1e-4 (sigma=0.001 kernel!)
    return (unsigned short)(u >> 16);
}
__device__ __forceinline__ float bf2f(unsigned int s) {
    return __uint_as_float(s << 16);
}
// async 16B global -> LDS (wave-uniform LDS base + lane*16; our per-thread ptr obeys that)
__device__ __forceinline__ void gld_lds16(const unsigned short* g, unsigned short* l) {
    __builtin_amdgcn_global_load_lds(
        (const __attribute__((address_space(1))) unsigned int*)g,
        (__attribute__((address_space(3))) unsigned int*)l, 16, 0, 0);
}

// ---------------------------------------------------------------------------
// K1 (merged prologue):
//   blocks [0,5200):  L2-normalize hiddens rows -> bf16 (130 rows per n)
//   blocks [5200,5968): Wg1 -> bf16
//   blocks [5968,6768): Xg pooled half
// ---------------------------------------------------------------------------
__global__ __launch_bounds__(256) void k_prologue(const float* __restrict__ hid,
        unsigned short* __restrict__ hnbf, const float* __restrict__ wg1,
        unsigned short* __restrict__ wg1b, const float* __restrict__ pooled,
        unsigned short* __restrict__ xg) {
    int bid = blockIdx.x, tid = threadIdx.x;
    if (bid < 5200) {
        int wave = tid >> 6, lane = tid & 63;
        int r = bid * 4 + wave;          // 0 .. 20800
        if (r >= 160 * LL) return;
        const float4* s4 = (const float4*)(hid + (size_t)r * HH);
        float4 v0 = s4[lane], v1 = s4[lane + 64], v2 = s4[lane + 128];
        float ss = v0.x*v0.x + v0.y*v0.y + v0.z*v0.z + v0.w*v0.w
                 + v1.x*v1.x + v1.y*v1.y + v1.z*v1.z + v1.w*v1.w
                 + v2.x*v2.x + v2.y*v2.y + v2.z*v2.z + v2.w*v2.w;
        #pragma unroll
        for (int m = 1; m < 64; m <<= 1) ss += __shfl_xor(ss, m, 64);
        float sc = 1.0f / fmaxf(sqrtf(ss), 1e-12f);
        ushort4 o0, o1, o2;
        o0.x = f2bf(v0.x*sc); o0.y = f2bf(v0.y*sc); o0.z = f2bf(v0.z*sc); o0.w = f2bf(v0.w*sc);
        o1.x = f2bf(v1.x*sc); o1.y = f2bf(v1.y*sc); o1.z = f2bf(v1.z*sc); o1.w = f2bf(v1.w*sc);
        o2.x = f2bf(v2.x*sc); o2.y = f2bf(v2.y*sc); o2.z = f2bf(v2.z*sc); o2.w = f2bf(v2.w*sc);
        ushort4* d4 = (ushort4*)(hnbf + (size_t)r * HH);
        d4[lane] = o0; d4[lane + 64] = o1; d4[lane + 128] = o2;
    } else if (bid < 5968) {
        int idx = (bid - 5200) * 256 + tid;      // < 196608 exactly
        wg1b[idx] = f2bf(wg1[idx]);
    } else {
        int row = bid - 5968;                    // 0..799
        int bi = row / 5;
        const float* src = pooled + (size_t)bi * HH;
        unsigned short* dst = xg + (size_t)row * 1536;
        #pragma unroll
        for (int j = 0; j < 3; j++) { int h = tid + j * 256; dst[h] = f2bf(src[h]); }
    }
}

// ---------------------------------------------------------------------------
// K2: batched similarity GEMM, async-staged, BK=64, XCD-swizzled.
// block -> (b,e,i) with xcd = bid&7 owning b in [4*xcd, 4*xcd+4).
// S[q][d] (q<130, d<136) -> compact bf16 Sg[pair][130][136].
// LDS k-segment XOR swizzle applied on the GLOBAL side (wave-uniform LDS dst).
// ---------------------------------------------------------------------------
__global__ __launch_bounds__(256) void k_sim_gemm(const unsigned short* __restrict__ hnbf,
                                                  unsigned short* __restrict__ Sg) {
    int w = blockIdx.x;
    int xcd = w & 7, slot = w >> 3;            // 800 = 8*100
    int b = xcd * 4 + (slot / 25);
    int ei = slot % 25;
    int e = ei / 5, i = ei % 5;
    int pair = b * 25 + ei;
    const unsigned short* A = hnbf + (size_t)(b * 5 + e) * LL * HH;
    const unsigned short* B = hnbf + (size_t)(b * 5 + i) * LL * HH;
    __shared__ unsigned short As[160 * 64];
    __shared__ unsigned short Bs[160 * 64];
    int tid = threadIdx.x, lane = tid & 63, wave = tid >> 6;
    int quad = lane >> 4, l16 = lane & 15;
    int wm = (wave & 1) * 5, wn = (wave >> 1) * 5;
    f32x4 acc[5][5];
    #pragma unroll
    for (int mt = 0; mt < 5; mt++)
        #pragma unroll
        for (int nt = 0; nt < 5; nt++) acc[mt][nt] = (f32x4){0.f, 0.f, 0.f, 0.f};

    for (int k0 = 0; k0 < HH; k0 += 64) {
        // stage 160 rows x 64 k (each panel 20 KB) via async 16B DMA.
        // thread s=tid+it*256 (s<1280): row r=s>>3, lds seg p=s&7 holds global seg p^(r&7).
        #pragma unroll
        for (int it = 0; it < 5; it++) {
            int s = tid + it * 256;
            int r = s >> 3;
            int rs = (r < LL) ? r : 0;          // clamp: finite values, masked later
            int sgl = (s & 7) ^ (r & 7);
            const unsigned short* ga = A + (size_t)rs * HH + k0 + sgl * 8;
            const unsigned short* gb = B + (size_t)rs * HH + k0 + sgl * 8;
            gld_lds16(ga, &As[s * 8]);
            gld_lds16(gb, &Bs[s * 8]);
        }
        __syncthreads();
        #pragma unroll
        for (int kb = 0; kb < 2; kb++) {
            bf16x8 af[5], bfr[5];
            #pragma unroll
            for (int t = 0; t < 5; t++) {
                int ra = (wm + t) * 16 + l16;
                int rb = (wn + t) * 16 + l16;
                af[t]  = *(const bf16x8*)&As[ra * 64 + (((kb << 2) + quad) ^ (ra & 7)) * 8];
                bfr[t] = *(const bf16x8*)&Bs[rb * 64 + (((kb << 2) + quad) ^ (rb & 7)) * 8];
            }
            #pragma unroll
            for (int mt = 0; mt < 5; mt++)
                #pragma unroll
                for (int nt = 0; nt < 5; nt++)
                    acc[mt][nt] = __builtin_amdgcn_mfma_f32_16x16x32_bf16(af[mt], bfr[nt], acc[mt][nt], 0, 0, 0);
        }
        __syncthreads();
    }
    size_t base = (size_t)pair * SR * SD;
    #pragma unroll
    for (int mt = 0; mt < 5; mt++)
        #pragma unroll
        for (int nt = 0; nt < 5; nt++) {
            int R0 = (wm + mt) * 16 + quad * 4;
            int C = (wn + nt) * 16 + l16;
            if (C < SD) {
                #pragma unroll
                for (int reg = 0; reg < 4; reg++) {
                    int R = R0 + reg;
                    if (R < SR) Sg[base + (size_t)R * SD + C] = f2bf(acc[mt][nt][reg]);
                }
            }
        }
}

// ---------------------------------------------------------------------------
// K3: kernel-pool. grid 4000, XCD-swizzled to match k_sim_gemm's b placement.
// 26 rows per block, 8 lanes per row streaming 16B uint4 from compact Sg.
// Gaussian-grid trick: exp(-50(s-mu_k)^2) = C_k * u * r^(k-1),
//   u=exp(-50 s^2+95 s), r=exp(-10 s), C_k=exp(-50 mu_k^2); k=0 direct.
// ---------------------------------------------------------------------------
template <bool DIAG>
__device__ __forceinline__ void pool_body(
    int pair, int row, int lane8, bool live, int ne, int c,
    const unsigned short* __restrict__ Sg,
    const float* __restrict__ batt,
    float* __restrict__ score, float* __restrict__ selp, float* __restrict__ denp,
    const float* wdA, const float* wdE, const float* wqC,
    const float* WaL, const float* WsL, const float* CkL,
    float* redsel, float* redden) {

    const float LOG2E = 1.4426950408889634f;
    const float CA = -50.0f * LOG2E;
    const float CB = 95.0f * LOG2E;
    const float CR = -10.0f * LOG2E;
    const float C0 = -500000.0f * LOG2E;
    int tid = threadIdx.x;

    float a0[KK], a2[KK];
    #pragma unroll
    for (int k = 0; k < KK; k++) { a0[k] = 0.0f; a2[k] = 0.0f; }

    auto proc = [&](float s, int d) {
        float w = wdA[d];
        float w2 = DIAG ? wdE[d] : 0.0f;
        float pe = exp2f(fmaf(CB, s, CA * s * s));
        float rr = exp2f(CR * s);
        float sm1 = s - 1.0f;
        float e0 = exp2f(C0 * (sm1 * sm1));
        a0[0] = fmaf(w, e0, a0[0]);
        if (DIAG) a2[0] = fmaf(w2, e0, a2[0]);
        float p = pe;
        #pragma unroll
        for (int k = 1; k < KK; k++) {
            a0[k] = fmaf(w, p, a0[k]);
            if (DIAG) a2[k] = fmaf(w2, p, a2[k]);
            p *= rr;
        }
    };

    if (live) {
        const unsigned short* Srow = Sg + (size_t)pair * SR * SD + (size_t)row * SD;
        #pragma unroll
        for (int j = 0; j < 2; j++) {
            uint4 v = *(const uint4*)(Srow + lane8 * 8 + j * 64);
            int d0 = lane8 * 8 + j * 64;
            proc(bf2f(v.x & 0xFFFFu), d0 + 0); proc(bf2f(v.x >> 16), d0 + 1);
            proc(bf2f(v.y & 0xFFFFu), d0 + 2); proc(bf2f(v.y >> 16), d0 + 3);
            proc(bf2f(v.z & 0xFFFFu), d0 + 4); proc(bf2f(v.z >> 16), d0 + 5);
            proc(bf2f(v.w & 0xFFFFu), d0 + 6); proc(bf2f(v.w >> 16), d0 + 7);
        }
        proc(bf2f((unsigned int)Srow[128 + lane8]), 128 + lane8);  // d in [128,136)
    }
    #pragma unroll
    for (int k = 0; k < KK; k++) {
        a0[k] += __shfl_xor(a0[k], 1, 64);
        a0[k] += __shfl_xor(a0[k], 2, 64);
        a0[k] += __shfl_xor(a0[k], 4, 64);
        if (DIAG) {
            a2[k] += __shfl_xor(a2[k], 1, 64);
            a2[k] += __shfl_xor(a2[k], 2, 64);
            a2[k] += __shfl_xor(a2[k], 4, 64);
        }
    }
    float selv = 0.0f, denv = 0.0f;
    if (live && lane8 == 0) {
        float sc = batt[0];
        #pragma unroll
        for (int k = 0; k < KK; k++)
            sc += WaL[k] * __logf(fmaxf(CkL[k] * a0[k], 1e-10f));
        score[(size_t)pair * LP + row] = sc;
        if (DIAG) {
            float cq = 0.0f;
            #pragma unroll
            for (int k = 0; k < KK; k++)
                cq += WsL[k] * __logf(fmaxf(CkL[k] * a2[k], 1e-10f));
            selv = wqC[row] * cq;
            denv = wqC[row];
        }
    }
    if (DIAG) {
        #pragma unroll
        for (int m = 8; m < 64; m <<= 1) {
            selv += __shfl_xor(selv, m, 64);
            denv += __shfl_xor(denv, m, 64);
        }
        int wave = tid >> 6, lane = tid & 63;
        if (lane == 0) { redsel[wave] = selv; redden[wave] = denv; }
        __syncthreads();
        if (tid == 0) {
            selp[ne * 5 + c] = redsel[0] + redsel[1] + redsel[2] + redsel[3];
            denp[ne * 5 + c] = redden[0] + redden[1] + redden[2] + redden[3];
        }
    }
}

__global__ __launch_bounds__(256) void k_pool(const unsigned short* __restrict__ Sg,
        const int* __restrict__ msk, const int* __restrict__ seg,
        const float* __restrict__ Watt, const float* __restrict__ batt,
        const float* __restrict__ Wsel,
        float* __restrict__ score, float* __restrict__ selp, float* __restrict__ denp) {
    __shared__ float wdA[SD], wdE[SD], wqC[SD];
    __shared__ float WaL[KK], WsL[KK], CkL[KK];
    __shared__ float redsel[4], redden[4];
    int w = blockIdx.x;                       // 4000 = 8 * 500
    int xcd = w & 7, slot = w >> 3;
    int b = xcd * 4 + (slot / 125);
    int rem = slot % 125;
    int ei = rem / 5, c = rem % 5;
    int e = ei / 5, i = ei % 5;
    int pair = b * 25 + ei;
    int ne = b * 5 + e, ni = b * 5 + i;
    int tid = threadIdx.x;

    if (tid < SD) {
        int d = tid;
        wdA[d] = (d >= 1 && d < LL) ? (float)msk[ni * LL + d] : 0.0f;
        float mtE = (d >= 1 && d < LL) ? (float)msk[ne * LL + d] : 0.0f;
        float sgE = (d < LL) ? (float)seg[ne * LL + d] : 0.0f;
        wdE[d] = sgE * mtE;
        wqC[d] = (1.0f - sgE) * mtE;
    }
    if (tid < KK) {
        const float LOG2E = 1.4426950408889634f;
        WaL[tid] = Watt[tid];
        WsL[tid] = Wsel[tid];
        float mu = 0.95f - 0.1f * (tid - 1);
        CkL[tid] = (tid == 0) ? 1.0f : exp2f(-50.0f * LOG2E * mu * mu);
    }
    __syncthreads();

    int row = c * 26 + (tid >> 3);
    int lane8 = tid & 7;
    bool live = (tid < 208);               // 26 rows * 8 lanes

    if (e == i)
        pool_body<true>(pair, row, lane8, live, ne, c, Sg, batt, score, selp, denp,
                        wdA, wdE, wqC, WaL, WsL, CkL, redsel, redden);
    else
        pool_body<false>(pair, row, lane8, live, ne, c, Sg, batt, score, selp, denp,
                         wdA, wdE, wqC, WaL, WsL, CkL, redsel, redden);
}

// ---------------------------------------------------------------------------
// K4: masked softmax. one wave per (be,i): grid 800, block 64.
// ---------------------------------------------------------------------------
__global__ __launch_bounds__(64) void k_att(const float* __restrict__ score,
        const int* __restrict__ msk, float* __restrict__ attg) {
    int bid = blockIdx.x;                 // be*5 + i
    int be = bid / 5, ii = bid % 5;
    int b = be / 5, e = be % 5;
    const float* srow = score + ((size_t)(b * 5 + ii) * 5 + e) * LP;
    int lane = threadIdx.x;

    float v0, v1, v2 = -1e30f;
    {
        int q = lane;
        float mt = (q >= 1 && msk[be * LL + q] != 0) ? 1.0f : 0.0f;
        v0 = (mt > 0.0f) ? srow[q] : -1e4f;
    }
    {
        int q = lane + 64;
        float mt = (msk[be * LL + q] != 0) ? 1.0f : 0.0f;
        v1 = (mt > 0.0f) ? srow[q] : -1e4f;
    }
    if (lane < 2) {
        int q = lane + 128;
        float mt = (msk[be * LL + q] != 0) ? 1.0f : 0.0f;
        v2 = (mt > 0.0f) ? srow[q] : -1e4f;
    }
    float mx = fmaxf(v0, fmaxf(v1, v2));
    #pragma unroll
    for (int m = 1; m < 64; m <<= 1) mx = fmaxf(mx, __shfl_xor(mx, m, 64));
    float e0 = __expf(v0 - mx), e1 = __expf(v1 - mx);
    float e2 = (lane < 2) ? __expf(v2 - mx) : 0.0f;
    float Z = e0 + e1 + e2;
    #pragma unroll
    for (int m = 1; m < 64; m <<= 1) Z += __shfl_xor(Z, m, 64);
    float iz = 1.0f / Z;
    attg[(size_t)bid * LL + lane] = e0 * iz;
    attg[(size_t)bid * LL + lane + 64] = e1 * iz;
    if (lane < 2) attg[(size_t)bid * LL + lane + 128] = e2 * iz;
}

// ---------------------------------------------------------------------------
// K5: denoise: de[be,i,h] = sum_q att[be,i,q]*hid[be,q,h]. grid 480 (be,j).
// 4-q load batches for MLP + split accumulators.
// ---------------------------------------------------------------------------
__global__ __launch_bounds__(256) void k_den(const float* __restrict__ attg,
        const float* __restrict__ hid, float* __restrict__ dn,
        unsigned short* __restrict__ xg) {
    int bid = blockIdx.x;
    int be = bid / 3, j = bid % 3;
    int b = be / 5, e = be % 5;
    int tid = threadIdx.x;
    int h = j * 256 + tid;
    __shared__ float attl[5 * LL];
    for (int s = tid; s < 5 * LL; s += 256)
        attl[s] = attg[(size_t)(be * 5) * LL + s];
    __syncthreads();

    float accA[5] = {0.f, 0.f, 0.f, 0.f, 0.f};
    float accB[5] = {0.f, 0.f, 0.f, 0.f, 0.f};
    const float* hb = hid + (size_t)be * LL * HH + h;
    int q = 0;
    #pragma unroll 2
    for (; q + 4 <= LL; q += 4) {
        float h0 = hb[(size_t)(q + 0) * HH];
        float h1 = hb[(size_t)(q + 1) * HH];
        float h2 = hb[(size_t)(q + 2) * HH];
        float h3 = hb[(size_t)(q + 3) * HH];
        #pragma unroll
        for (int i = 0; i < 5; i++) {
            accA[i] = fmaf(attl[i * LL + q], h0, accA[i]);
            accB[i] = fmaf(attl[i * LL + q + 1], h1, accB[i]);
            accA[i] = fmaf(attl[i * LL + q + 2], h2, accA[i]);
            accB[i] = fmaf(attl[i * LL + q + 3], h3, accB[i]);
        }
    }
    for (; q < LL; q++) {
        float hv = hb[(size_t)q * HH];
        #pragma unroll
        for (int i = 0; i < 5; i++) accA[i] = fmaf(attl[i * LL + q], hv, accA[i]);
    }
    #pragma unroll
    for (int i = 0; i < 5; i++) {
        float v = accA[i] + accB[i];
        dn[((size_t)be * 5 + i) * HH + h] = v;
        xg[((size_t)(b * 5 + i) * 5 + e) * 1536 + HH + h] = f2bf(v);
    }
}

// ---------------------------------------------------------------------------
// K6: gating GEMM Cg[800][128] += Xg[800][1536] @ Wg1^T, 3-way K-split,
// f32 atomics into memset-zeroed cg. grid 150: bid = rb*3 + ks.
// ---------------------------------------------------------------------------
__global__ __launch_bounds__(256) void k_gate_gemm(const unsigned short* __restrict__ xg,
        const unsigned short* __restrict__ wg1b, float* __restrict__ cg) {
    int bid = blockIdx.x;
    int rb = bid / 3, ks = bid % 3;
    int m0 = rb * 16;
    __shared__ unsigned short As[16 * 32];
    __shared__ unsigned short Bs[128 * 32];
    int tid = threadIdx.x, lane = tid & 63, wave = tid >> 6;
    int quad = lane >> 4, l16 = lane & 15;
    f32x4 acc[2];
    acc[0] = (f32x4){0.f, 0.f, 0.f, 0.f};
    acc[1] = (f32x4){0.f, 0.f, 0.f, 0.f};

    for (int t = 0; t < 16; t++) {
        int k0 = ks * 512 + t * 32;
        if (tid < 64) {
            int row = tid >> 2, sg = tid & 3;
            *(uint4*)&As[tid * 8] = *(const uint4*)(xg + (size_t)(m0 + row) * 1536 + k0 + sg * 8);
        }
        #pragma unroll
        for (int it = 0; it < 2; it++) {
            int s = tid + it * 256;
            int row = s >> 2, sg = s & 3;
            *(uint4*)&Bs[s * 8] = *(const uint4*)(wg1b + (size_t)row * 1536 + k0 + sg * 8);
        }
        __syncthreads();
        bf16x8 af = *(const bf16x8*)&As[l16 * 32 + quad * 8];
        #pragma unroll
        for (int nt = 0; nt < 2; nt++) {
            int ct = wave * 2 + nt;
            bf16x8 bfr = *(const bf16x8*)&Bs[(ct * 16 + l16) * 32 + quad * 8];
            acc[nt] = __builtin_amdgcn_mfma_f32_16x16x32_bf16(af, bfr, acc[nt], 0, 0, 0);
        }
        __syncthreads();
    }
    #pragma unroll
    for (int nt = 0; nt < 2; nt++) {
        int C = (wave * 2 + nt) * 16 + l16;
        #pragma unroll
        for (int reg = 0; reg < 4; reg++) {
            int R = m0 + quad * 4 + reg;
            atomicAdd(&cg[(size_t)R * 128 + C], acc[nt][reg]);
        }
    }
}

// ---------------------------------------------------------------------------
// K7: per (b,i): g[e] = Wg2.relu(cg+bg1)+bg2; softmax_e; de; feat = Wd.concat
// ---------------------------------------------------------------------------
__global__ __launch_bounds__(256) void k_gate_epi(const float* __restrict__ cg,
        const float* __restrict__ bg1, const float* __restrict__ wg2,
        const float* __restrict__ bg2, const float* __restrict__ dn,
        const float* __restrict__ pooled, const float* __restrict__ wd,
        const float* __restrict__ bd, float* __restrict__ feat) {
    int bi = blockIdx.x;                 // b*5+i
    int b = bi / 5, ii = bi % 5;
    __shared__ float red4[4];
    __shared__ float gL[5];
    __shared__ float deL[HH];
    int tid = threadIdx.x, lane = tid & 63, wave = tid >> 6;

    for (int e = 0; e < 5; e++) {
        float v = 0.0f;
        if (tid < 128) {
            float ccv = cg[(size_t)(bi * 5 + e) * 128 + tid] + bg1[tid];
            v = wg2[tid] * fmaxf(ccv, 0.0f);
        }
        #pragma unroll
        for (int m = 1; m < 64; m <<= 1) v += __shfl_xor(v, m, 64);
        if (lane == 0) red4[wave] = v;
        __syncthreads();
        if (tid == 0) gL[e] = red4[0] + red4[1] + bg2[0];
        __syncthreads();
    }
    float mx = gL[0];
    #pragma unroll
    for (int e = 1; e < 5; e++) mx = fmaxf(mx, gL[e]);
    float wde[5]; float z = 0.0f;
    #pragma unroll
    for (int e = 0; e < 5; e++) { wde[e] = __expf(gL[e] - mx); z += wde[e]; }
    float iz = 1.0f / z;
    #pragma unroll
    for (int e = 0; e < 5; e++) wde[e] *= iz;

    #pragma unroll
    for (int j = 0; j < 3; j++) {
        int h = tid + j * 256;
        float v = 0.0f;
        #pragma unroll
        for (int e = 0; e < 5; e++)
            v += wde[e] * dn[((size_t)(b * 5 + e) * 5 + ii) * HH + h];
        deL[h] = v;
    }
    __syncthreads();

    float part[3] = {0.0f, 0.0f, 0.0f};
    #pragma unroll
    for (int mm = 0; mm < 6; mm++) {
        int h = tid + mm * 256;
        float x = (mm < 3) ? pooled[(size_t)bi * HH + h] : deL[h - HH];
        #pragma unroll
        for (int c = 0; c < 3; c++) part[c] = fmaf(x, wd[(size_t)c * 1536 + h], part[c]);
    }
    #pragma unroll
    for (int c = 0; c < 3; c++) {
        float v = part[c];
        #pragma unroll
        for (int m = 1; m < 64; m <<= 1) v += __shfl_xor(v, m, 64);
        if (lane == 0) red4[wave] = v;
        __syncthreads();
        if (tid == 0) feat[bi * 3 + c] = red4[0] + red4[1] + red4[2] + red4[3] + bd[c];
        __syncthreads();
    }
}

// ---------------------------------------------------------------------------
// K8: final: sel from partials, select softmax over i, class softmax, log
// ---------------------------------------------------------------------------
__global__ __launch_bounds__(64) void k_final(const float* __restrict__ selp,
        const float* __restrict__ denp, const float* __restrict__ bsel,
        const float* __restrict__ feat, float* __restrict__ out) {
    int b = threadIdx.x;
    if (b >= BB) return;
    float sv[5]; float m = -1e30f;
    #pragma unroll
    for (int i = 0; i < 5; i++) {
        float num = 0.0f, den = 0.0f;
        #pragma unroll
        for (int c = 0; c < 5; c++) {
            num += selp[(b * 5 + i) * 5 + c];
            den += denp[(b * 5 + i) * 5 + c];
        }
        sv[i] = bsel[0] + num / (den + 1e-10f);
        m = fmaxf(m, sv[i]);
    }
    float z = 0.0f;
    #pragma unroll
    for (int i = 0; i < 5; i++) { sv[i] = __expf(sv[i] - m); z += sv[i]; }
    #pragma unroll
    for (int i = 0; i < 5; i++) sv[i] /= z;
    float prob[3] = {0.0f, 0.0f, 0.0f};
    #pragma unroll
    for (int i = 0; i < 5; i++) {
        float f0 = feat[(b * 5 + i) * 3 + 0];
        float f1 = feat[(b * 5 + i) * 3 + 1];
        float f2 = feat[(b * 5 + i) * 3 + 2];
        float mm = fmaxf(f0, fmaxf(f1, f2));
        float e0 = __expf(f0 - mm), e1 = __expf(f1 - mm), e2 = __expf(f2 - mm);
        float zz = e0 + e1 + e2;
        prob[0] += sv[i] * e0 / zz;
        prob[1] += sv[i] * e1 / zz;
        prob[2] += sv[i] * e2 / zz;
    }
    #pragma unroll
    for (int c = 0; c < 3; c++) out[b * 3 + c] = __logf(prob[c]);
}

// ---------------------------------------------------------------------------
extern "C" void kernel_launch(void* const* d_in, const int* in_sizes, int n_in,
                              void* d_out, int out_size, void* d_ws, size_t ws_size,
                              hipStream_t stream) {
    const float* hiddens = (const float*)d_in[0];
    const float* pooled  = (const float*)d_in[1];
    const int*   msk     = (const int*)d_in[2];
    const int*   seg     = (const int*)d_in[3];
    const float* Watt    = (const float*)d_in[4];
    const float* batt    = (const float*)d_in[5];
    const float* Wsel    = (const float*)d_in[6];
    const float* bsel    = (const float*)d_in[7];
    const float* Wg1     = (const float*)d_in[8];
    const float* bg1     = (const float*)d_in[9];
    const float* Wg2     = (const float*)d_in[10];
    const float* bg2     = (const float*)d_in[11];
    const float* Wd      = (const float*)d_in[12];
    const float* bd      = (const float*)d_in[13];

    char* ws = (char*)d_ws;
    size_t off = 0;
    auto alloc = [&](size_t bytes) -> void* {
        void* p = ws + off;
        off += (bytes + 255) & ~(size_t)255;
        return p;
    };
    unsigned short* hnbf   = (unsigned short*)alloc((size_t)160 * LL * HH * 2);  // 31.9 MB
    unsigned short* Sg     = (unsigned short*)alloc((size_t)800 * SR * SD * 2);  // 28.3 MB
    float*          score  = (float*)alloc((size_t)800 * LP * 4);
    float*          selp   = (float*)alloc((size_t)160 * 5 * 4);
    float*          denp   = (float*)alloc((size_t)160 * 5 * 4);
    float*          attg   = (float*)alloc((size_t)800 * LL * 4);
    float*          dn     = (float*)alloc((size_t)160 * 5 * HH * 4);            // 2.46 MB
    unsigned short* xg     = (unsigned short*)alloc((size_t)800 * 1536 * 2);
    unsigned short* wg1b   = (unsigned short*)alloc((size_t)128 * 1536 * 2);
    float*          cg     = (float*)alloc((size_t)800 * 128 * 4);
    float*          feat   = (float*)alloc((size_t)800 * 3 * 4);
    (void)ws_size; (void)in_sizes; (void)n_in; (void)out_size;

    hipMemsetAsync(cg, 0, (size_t)800 * 128 * 4, stream);
    k_prologue<<<dim3(6768), dim3(256), 0, stream>>>(hiddens, hnbf, Wg1, wg1b, pooled, xg);
    k_sim_gemm<<<dim3(800), dim3(256), 0, stream>>>(hnbf, Sg);
    k_pool<<<dim3(4000), dim3(256), 0, stream>>>(Sg, msk, seg, Watt, batt, Wsel, score, selp, denp);
    k_att<<<dim3(800), dim3(64), 0, stream>>>(score, msk, attg);
    k_den<<<dim3(480), dim3(256), 0, stream>>>(attg, hiddens, dn, xg);
    k_gate_gemm<<<dim3(150), dim3(256), 0, stream>>>(xg, wg1b, cg);
    k_gate_epi<<<dim3(160), dim3(256), 0, stream>>>(cg, bg1, Wg2, bg2, dn, pooled, Wd, bd, feat);
    k_final<<<dim3(1), dim3(64), 0, stream>>>(selp, denp, bsel, feat, (float*)d_out);
}